// Round 8
// baseline (386.529 us; speedup 1.0000x reference)
//
#include <hip/hip_runtime.h>
#include <cstddef>

#define BB 64
#define NN 1024
#define CC 256
#define KK 512
#define TT 64
#define NPAIR 128

typedef _Float16 h8 __attribute__((ext_vector_type(8)));
typedef _Float16 h4 __attribute__((ext_vector_type(4)));
typedef float f4 __attribute__((ext_vector_type(4)));

// async global->LDS, 16B per lane; LDS dest = wave-uniform base + lane*16
typedef __attribute__((address_space(1))) const void GV;
typedef __attribute__((address_space(3))) void LV;
#define GLDS16(g, s) __builtin_amdgcn_global_load_lds((GV*)(const void*)(g), (LV*)(void*)(s), 16, 0, 0)

// ---------------- ws layout (float words) ----------------
// feath   : 0          size 4194304  (8388608 f16: 32768 x 256 hi)
// featl   : 4194304    size 4194304  (lo plane)
// normF   : 8388608    size 32768
// centk   : 8421376    size B*K*4   = 131072   (x,y,z,|c|^2)
// sbuf    : 8552448    size 65536   (T*2*K)
// topidx  : 8617984    size 32768   (int)
// neff    : 8650752    size 64      (int)
// corr    : 8650816    size 65536   (int)
// gmask   : 8716352    size NPAIR*K*16 = 1048576 (uint)
//   aliased into gmask region (all consumed before geo_kernel overwrites):
//   partv = +0 (262144), partl = +262144, partd = +524288
//   wth   = +786432 (32768 words = 65536 f16), wtl = +819200
// total 9764928 words = 39.06 MB

// ===================== stage 0: W_in transpose + f16 split =====================
__global__ __launch_bounds__(256) void wtrans_kernel(
    const float* __restrict__ Win, _Float16* __restrict__ wth, _Float16* __restrict__ wtl)
{
    __shared__ float t[64][65];
    const int k0 = blockIdx.x * 64, n0 = blockIdx.y * 64;
    const int tid = threadIdx.x;
    const int c = tid & 63, r0 = tid >> 6;
    for (int r = r0; r < 64; r += 4)
        t[r][c] = Win[(size_t)(k0 + r) * CC + n0 + c];
    __syncthreads();
    for (int r = r0; r < 64; r += 4) {
        float x = t[c][r];                     // x = Win[k0+c][n0+r]
        _Float16 h = (_Float16)x;
        size_t o = (size_t)(n0 + r) * CC + k0 + c;
        wth[o] = h;
        wtl[o] = (_Float16)(x - (float)h);
    }
}

// ===================== stage 1: selection =====================
__global__ __launch_bounds__(512) void sel_kernel(
    const float* __restrict__ attn, const float* __restrict__ cents,
    const float* __restrict__ sas, const int* __restrict__ num_rt,
    int* __restrict__ topidx, int* __restrict__ neff, float* __restrict__ centk)
{
    __shared__ unsigned long long keys[1024];
    const int b = blockIdx.x, tid = threadIdx.x;
    const int nr = num_rt[b];
    for (int i = tid; i < 1024; i += 512) {
        float a = (i < nr) ? attn[b * NN + i] : -1e9f;
        unsigned u = __float_as_uint(a);
        u = (u & 0x80000000u) ? ~u : (u | 0x80000000u);
        keys[i] = ((unsigned long long)u << 32) | (unsigned)(0xFFFFFFFFu - (unsigned)i);
    }
    __syncthreads();
    for (int k = 2; k <= 1024; k <<= 1) {
        for (int j = k >> 1; j > 0; j >>= 1) {
            int i = ((tid & ~(j - 1)) << 1) | (tid & (j - 1));
            int p = i | j;
            unsigned long long a = keys[i], c = keys[p];
            bool up = (i & k) == 0;
            if (up ? (a < c) : (a > c)) { keys[i] = c; keys[p] = a; }
            __syncthreads();
        }
    }
    {
        unsigned long long key = keys[tid];
        int idx = (int)(~(unsigned)key);
        float x = cents[(b * NN + idx) * 3 + 0];
        float y = cents[(b * NN + idx) * 3 + 1];
        float z = cents[(b * NN + idx) * 3 + 2];
        if (idx < nr) {
            float sc = sas[b * 4 + 3];
            x = x * sc + sas[b * 4 + 0];
            y = y * sc + sas[b * 4 + 1];
            z = z * sc + sas[b * 4 + 2];
        }
        float nc = x * x + y * y + z * z;
        ((float4*)centk)[b * KK + tid] = make_float4(x, y, z, nc);
        topidx[b * KK + tid] = idx;
    }
    if (tid == 0) neff[b] = (nr < KK) ? nr : KK;
}

// ===================== stage 2: feat = rt_k @ W_in + b_in via split-f16 MFMA ====
// waves 0,1: A rows load+split (f32 source); waves 2,3: async-stage Bh/Bl
__global__ __launch_bounds__(256) void feat_mfma(
    const float* __restrict__ rt, const int* __restrict__ topidx,
    const _Float16* __restrict__ wth, const _Float16* __restrict__ wtl,
    const float* __restrict__ bin,
    _Float16* __restrict__ feath, _Float16* __restrict__ featl)
{
    const int mtile = blockIdx.x, nt = blockIdx.y;
    __shared__ _Float16 Ah[128][32], Al[128][32], Bh[128][32], Bl[128][32];
    __shared__ int tix[128];
    const int tid = threadIdx.x;
    const int w = tid >> 6, lane = tid & 63;
    const int quad = lane >> 4, l16 = lane & 15;
    const int wm = (w >> 1) * 64, wl = (w & 1) * 64;
    const int b = mtile >> 2;
    if (tid < 128) tix[tid] = topidx[mtile * 128 + tid];
    __syncthreads();
    const float* arow = (tid < 128) ? rt + ((size_t)b * NN + tix[tid]) * CC : rt;
    const _Float16* bplane = (w == 2) ? wth : wtl;
    _Float16* bsh = (w == 2) ? &Bh[0][0] : &Bl[0][0];
    const int rowi = lane >> 2, chunk = lane & 3;

    f4 acc[4][4];
    #pragma unroll
    for (int i = 0; i < 4; i++)
        #pragma unroll
        for (int j = 0; j < 4; j++)
            acc[i][j] = (f4){0.f, 0.f, 0.f, 0.f};

    for (int k0 = 0; k0 < CC; k0 += 32) {
        __syncthreads();
        if (w < 2) {
            const float4* src = (const float4*)(arow + k0);
            #pragma unroll
            for (int c = 0; c < 4; c++) {
                float4 p = src[2 * c], q2 = src[2 * c + 1];
                float xv[8] = {p.x, p.y, p.z, p.w, q2.x, q2.y, q2.z, q2.w};
                h8 hv, lv;
                #pragma unroll
                for (int j = 0; j < 8; j++) {
                    _Float16 h = (_Float16)xv[j];
                    hv[j] = h;
                    lv[j] = (_Float16)(xv[j] - (float)h);
                }
                *(h8*)&Ah[tid][c * 8] = hv;
                *(h8*)&Al[tid][c * 8] = lv;
            }
        } else {
            #pragma unroll
            for (int j = 0; j < 8; j++) {
                int row = j * 16 + rowi;
                const _Float16* ga = bplane + (size_t)(nt * 128 + row) * CC + k0 + chunk * 8;
                GLDS16(ga, bsh + j * 512);
            }
        }
        __syncthreads();
        h8 afh[4], afl[4], bfh[4], bfl[4];
        #pragma unroll
        for (int i = 0; i < 4; i++) {
            int ra = wm + i * 16 + l16;
            int rb = wl + i * 16 + l16;
            afh[i] = *(const h8*)&Ah[ra][quad * 8];
            afl[i] = *(const h8*)&Al[ra][quad * 8];
            bfh[i] = *(const h8*)&Bh[rb][quad * 8];
            bfl[i] = *(const h8*)&Bl[rb][quad * 8];
        }
        #pragma unroll
        for (int i = 0; i < 4; i++)
            #pragma unroll
            for (int j = 0; j < 4; j++) {
                acc[i][j] = __builtin_amdgcn_mfma_f32_16x16x32_f16(afh[i], bfh[j], acc[i][j], 0, 0, 0);
                acc[i][j] = __builtin_amdgcn_mfma_f32_16x16x32_f16(afh[i], bfl[j], acc[i][j], 0, 0, 0);
                acc[i][j] = __builtin_amdgcn_mfma_f32_16x16x32_f16(afl[i], bfh[j], acc[i][j], 0, 0, 0);
            }
    }
    #pragma unroll
    for (int j = 0; j < 4; j++) {
        int col = wl + j * 16 + l16;
        float bj = bin[nt * 128 + col];
        #pragma unroll
        for (int i = 0; i < 4; i++)
            #pragma unroll
            for (int r = 0; r < 4; r++) {
                int row = wm + i * 16 + quad * 4 + r;
                float v = acc[i][j][r] + bj;
                _Float16 h = (_Float16)v;
                size_t o = (size_t)(mtile * 128 + row) * CC + nt * 128 + col;
                feath[o] = h;
                featl[o] = (_Float16)(v - (float)h);
            }
    }
}

// ===================== stage 2b: row norms from hi/lo =====================
__global__ __launch_bounds__(256) void norm_kernel(
    const _Float16* __restrict__ feath, const _Float16* __restrict__ featl,
    float* __restrict__ normF)
{
    int r = blockIdx.x * 4 + (threadIdx.x >> 6);
    int lane = threadIdx.x & 63;
    h4 hv = ((const h4*)(feath + (size_t)r * CC))[lane];
    h4 lv = ((const h4*)(featl + (size_t)r * CC))[lane];
    float s = 0.f;
    #pragma unroll
    for (int j = 0; j < 4; j++) {
        float x = (float)hv[j] + (float)lv[j];
        s += x * x;
    }
    for (int off = 32; off; off >>= 1) s += __shfl_down(s, off);
    if (lane == 0) normF[r] = s;
}

// ===================== stage 3a: fd argmin via split-f16 MFMA =====================
// Merged pos/neg block (shared anchor A-tile): 512 threads = 8 waves,
// wave = (pair, wm, wl) in 2x2x2. grid (4 lt, 4 kt, 64 t).
// Staging: waves 0..5 async-load the 6 planes {Ah,Al,Ph,Pl,Nh,Nl}.
__global__ __launch_bounds__(512) void argmin_mfma(
    const _Float16* __restrict__ feath, const _Float16* __restrict__ featl,
    const float* __restrict__ normF,
    const int* __restrict__ anc, const int* __restrict__ pos, const int* __restrict__ neg,
    float* __restrict__ partv, int* __restrict__ partl, float* __restrict__ partd)
{
    const int lt = blockIdx.x, kt = blockIdx.y, t = blockIdx.z;
    const int a = anc[t], bp = pos[t], bn = neg[t];
    const size_t Abase = ((size_t)a * KK + kt * 128) * CC;
    const size_t Pbase = ((size_t)bp * KK + lt * 128) * CC;
    const size_t Nbase = ((size_t)bn * KK + lt * 128) * CC;
    __shared__ _Float16 smem[6 * 4096];    // 6 planes of [128][32] f16
    __shared__ float rdv[2][128][2];
    __shared__ int   rdl[2][128][2];
    __shared__ float rdd[2][128][2];
    const int tid = threadIdx.x;
    const int w = tid >> 6, lane = tid & 63;
    const int quad = lane >> 4, l16 = lane & 15;
    const int pair = w & 1, wmI = (w >> 1) & 1, wlI = (w >> 2) & 1;
    const int wm = wmI * 64, wl = wlI * 64;
    const int rowi = lane >> 2, chunk = lane & 3;
    const _Float16* gplane =
        (w == 0) ? feath + Abase : (w == 1) ? featl + Abase :
        (w == 2) ? feath + Pbase : (w == 3) ? featl + Pbase :
        (w == 4) ? feath + Nbase : featl + Nbase;
    _Float16* splane = smem + (w < 6 ? w : 0) * 4096;
    const _Float16* grow = gplane + (size_t)rowi * CC + chunk * 8;
    const _Float16* Ah = smem;
    const _Float16* Al = smem + 4096;
    const _Float16* Bhp = smem + (pair ? 4 : 2) * 4096;
    const _Float16* Blp = smem + (pair ? 5 : 3) * 4096;
    const int bb = pair ? bn : bp;

    f4 acc[4][4];
    #pragma unroll
    for (int i = 0; i < 4; i++)
        #pragma unroll
        for (int j = 0; j < 4; j++)
            acc[i][j] = (f4){0.f, 0.f, 0.f, 0.f};

    for (int k0 = 0; k0 < CC; k0 += 32) {
        __syncthreads();
        if (w < 6) {
            #pragma unroll
            for (int j = 0; j < 8; j++)
                GLDS16(grow + (size_t)(j * 16) * CC + k0, splane + j * 512);
        }
        __syncthreads();
        h8 afh[4], afl[4], bfh[4], bfl[4];
        #pragma unroll
        for (int i = 0; i < 4; i++) {
            int ra = wm + i * 16 + l16;
            int rb = wl + i * 16 + l16;
            afh[i] = *(const h8*)&Ah[ra * 32 + quad * 8];
            afl[i] = *(const h8*)&Al[ra * 32 + quad * 8];
            bfh[i] = *(const h8*)&Bhp[rb * 32 + quad * 8];
            bfl[i] = *(const h8*)&Blp[rb * 32 + quad * 8];
        }
        #pragma unroll
        for (int i = 0; i < 4; i++)
            #pragma unroll
            for (int j = 0; j < 4; j++) {
                acc[i][j] = __builtin_amdgcn_mfma_f32_16x16x32_f16(afh[i], bfh[j], acc[i][j], 0, 0, 0);
                acc[i][j] = __builtin_amdgcn_mfma_f32_16x16x32_f16(afh[i], bfl[j], acc[i][j], 0, 0, 0);
                acc[i][j] = __builtin_amdgcn_mfma_f32_16x16x32_f16(afl[i], bfh[j], acc[i][j], 0, 0, 0);
            }
    }
    float nbj[4];
    #pragma unroll
    for (int j = 0; j < 4; j++)
        nbj[j] = normF[(size_t)bb * KK + lt * 128 + wl + j * 16 + l16];
    #pragma unroll
    for (int i = 0; i < 4; i++) {
        #pragma unroll
        for (int r = 0; r < 4; r++) {
            float bv = INFINITY; int bl = 0; float bd = 0.f;
            #pragma unroll
            for (int j = 0; j < 4; j++) {
                float d = acc[i][j][r];
                float v = nbj[j] - 2.f * d;
                int l = lt * 128 + wl + j * 16 + l16;
                if (v < bv) { bv = v; bl = l; bd = d; }
            }
            #pragma unroll
            for (int off = 1; off < 16; off <<= 1) {
                float ov = __shfl_xor(bv, off);
                int   ol = __shfl_xor(bl, off);
                float od = __shfl_xor(bd, off);
                if (ov < bv || (ov == bv && ol < bl)) { bv = ov; bl = ol; bd = od; }
            }
            if (l16 == 0) {
                int row = wm + i * 16 + quad * 4 + r;
                rdv[pair][row][wlI] = bv;
                rdl[pair][row][wlI] = bl;
                rdd[pair][row][wlI] = bd;
            }
        }
    }
    __syncthreads();
    if (tid < 256) {
        const int pairIdx = tid >> 7, row = tid & 127;
        float bv = rdv[pairIdx][row][0]; int bl = rdl[pairIdx][row][0]; float bd = rdd[pairIdx][row][0];
        float v1 = rdv[pairIdx][row][1]; int l1 = rdl[pairIdx][row][1];
        if (v1 < bv || (v1 == bv && l1 < bl)) { bv = v1; bl = l1; bd = rdd[pairIdx][row][1]; }
        int pr = t * 2 + pairIdx;
        size_t idx = (((size_t)pr * 4 + kt) * 128 + row) * 4 + lt;
        partv[idx] = bv; partl[idx] = bl; partd[idx] = bd;
    }
}

// ===================== stage 3b: merge l-tiles, emit corr + s =====================
__global__ __launch_bounds__(256) void argmin_fin(
    const float* __restrict__ partv, const int* __restrict__ partl,
    const float* __restrict__ partd, const float* __restrict__ normF,
    const int* __restrict__ anc, const int* __restrict__ pos, const int* __restrict__ neg,
    int* __restrict__ corr, float* __restrict__ sbuf)
{
    int g = blockIdx.x * 256 + threadIdx.x;
    int pr = g >> 9, kg = g & 511;
    int t = pr >> 1, nn2 = pr & 1;
    int a = anc[t];
    int bb = nn2 ? neg[t] : pos[t];
    size_t base = (size_t)g * 4;
    float bv = partv[base]; int bl = partl[base]; float bd = partd[base];
    #pragma unroll
    for (int lt = 1; lt < 4; lt++) {
        float v = partv[base + lt]; int l = partl[base + lt];
        if (v < bv || (v == bv && l < bl)) { bv = v; bl = l; bd = partd[base + lt]; }
    }
    float na = normF[(size_t)a * KK + kg];
    float nb = normF[(size_t)bb * KK + bl];
    float cosv = bd / (sqrtf(na) * sqrtf(nb) + 1e-8f);
    corr[g] = bl;
    sbuf[g] = fmaxf(cosv, 0.f);
}

// ===================== stage 4: geo bitmask =====================
// grid (2 kt, 4 lt, 128 pair) = 1024 blocks -> 4 blocks/CU, 16 waves/CU
__global__ __launch_bounds__(256) void geo_kernel(
    const float* __restrict__ centk, const int* __restrict__ corr,
    const int* __restrict__ neff,
    const int* __restrict__ anc, const int* __restrict__ pos, const int* __restrict__ neg,
    unsigned* __restrict__ gmask)
{
    const int kt = blockIdx.x;          // 0..1 (256 rows)
    const int lt = blockIdx.y;          // 0..3 (128 cols)
    const int pair = blockIdx.z;        // 0..127
    const int t = pair >> 1, nn2 = pair & 1;
    const int a = anc[t];
    const int bb2 = (nn2 == 0) ? pos[t] : neg[t];
    const int nea = neff[a], neb = neff[bb2];
    __shared__ __align__(16) float4 ca[512], cq[512];
    for (int i = threadIdx.x; i < KK; i += 256) {
        ca[i] = ((const float4*)centk)[a * KK + i];
        int c = corr[pair * KK + i];
        cq[i] = ((const float4*)centk)[bb2 * KK + c];
    }
    __syncthreads();
    const int k = kt * 256 + threadIdx.x;
    float4 pk = ca[k], qk = cq[k];
    bool rowm = k < nea;
    unsigned* outp = gmask + ((size_t)pair * KK + k) * 16 + lt * 4;
    for (int w = 0; w < 4; w++) {
        unsigned word = 0;
        #pragma unroll
        for (int bi = 0; bi < 32; bi++) {
            int l = lt * 128 + w * 32 + bi;
            float4 pl = ca[l], ql = cq[l];
            float dp2 = pk.w + pl.w - 2.f * (pk.x * pl.x + pk.y * pl.y + pk.z * pl.z);
            float dp = sqrtf(fmaxf(dp2, 0.f) + 1e-12f);
            float dq2 = qk.w + ql.w - 2.f * (qk.x * ql.x + qk.y * ql.y + qk.z * ql.z);
            float dq = sqrtf(fmaxf(dq2, 0.f) + 1e-12f);
            bool g = (fabsf(dp - dq) < 0.5f) && rowm && (l < neb) && (l != k);
            word |= (g ? (1u << bi) : 0u);
        }
        outp[w] = word;
    }
}

// ===================== stage 5: power iteration + sort + MLP =====================
__global__ __launch_bounds__(1024, 4) void power_kernel(
    const unsigned* __restrict__ gmask, const float* __restrict__ sbuf,
    const float* __restrict__ W1, const float* __restrict__ b1,
    const float* __restrict__ W2, const float* __restrict__ b2,
    float* __restrict__ out)
{
    const int pair = blockIdx.x;
    const int tid = threadIdx.x;
    const int row = tid & 511;
    const int half = tid >> 9;
    __shared__ __align__(16) float u[512];
    __shared__ float T[64][257];
    __shared__ float pacc[1024];
    __shared__ float red[16];
    __shared__ float ev[512];
    __shared__ float hpart[1024];
    unsigned m[8];
    const unsigned* g = gmask + ((size_t)pair * KK + row) * 16 + half * 8;
    #pragma unroll
    for (int w = 0; w < 8; w++) m[w] = g[w];
    const float s = sbuf[pair * KK + row];
    const int bp = tid & 63;
    const int vh = tid >> 6;
    const int GV_[16] = {0,1,3,2,6,7,5,4,12,13,15,14,10,11,9,8};
    const int GB[15] = {0,1,0,2,0,1,0,3,0,1,0,2,0,1,0};
    const float GS[15] = {1.f,1.f,-1.f,1.f,1.f,-1.f,-1.f,1.f,1.f,1.f,-1.f,-1.f,1.f,-1.f,-1.f};
    float v = 0.044194173824159216f;   // 1/sqrt(512)
    if (half == 0) u[row] = s * v;
    __syncthreads();
    for (int it = 0; it < 20; it++) {
        {
            float4 ulo = *(const float4*)&u[bp * 8];
            float4 uhi = *(const float4*)&u[bp * 8 + 4];
            float ul[4] = {ulo.x, ulo.y, ulo.z, ulo.w};
            float H = 0.f;
            H += (float)((vh >> 0) & 1) * uhi.x;
            H += (float)((vh >> 1) & 1) * uhi.y;
            H += (float)((vh >> 2) & 1) * uhi.z;
            H += (float)((vh >> 3) & 1) * uhi.w;
            float L = 0.f;
            T[bp][vh * 16 + 0] = H;
            #pragma unroll
            for (int k = 1; k < 16; k++) {
                L += GS[k - 1] * ul[GB[k - 1]];
                T[bp][vh * 16 + GV_[k]] = H + L;
            }
        }
        __syncthreads();
        float a0 = 0.f, a1 = 0.f, a2 = 0.f, a3 = 0.f;
        #pragma unroll
        for (int w = 0; w < 8; w++) {
            unsigned mw = m[w];
            const int p0 = half * 32 + w * 4;
            a0 += T[p0 + 0][mw & 255u];
            a1 += T[p0 + 1][(mw >> 8) & 255u];
            a2 += T[p0 + 2][(mw >> 16) & 255u];
            a3 += T[p0 + 3][mw >> 24];
        }
        pacc[tid] = (a0 + a1) + (a2 + a3);
        __syncthreads();
        float wk = s * (pacc[row] + pacc[row + 512]);
        float t2 = wk * wk;
        for (int off = 32; off; off >>= 1) t2 += __shfl_down(t2, off);
        if ((tid & 63) == 0) red[tid >> 6] = t2;
        __syncthreads();
        float tot = 0.f;
        #pragma unroll
        for (int x = 0; x < 16; x++) tot += red[x];
        tot *= 0.5f;
        v = wk / (sqrtf(tot) + 1e-8f);
        if (half == 0) u[row] = s * v;
        __syncthreads();
    }
    if (half == 0) ev[row] = v;
    __syncthreads();
    for (int kk = 2; kk <= 512; kk <<= 1) {
        for (int j = kk >> 1; j; j >>= 1) {
            if (tid < 256) {
                int i = ((tid & ~(j - 1)) << 1) | (tid & (j - 1));
                int p = i | j;
                float x = ev[i], y = ev[p];
                bool up = (i & kk) == 0;
                if (up ? (x < y) : (x > y)) { ev[i] = y; ev[p] = x; }
            }
            __syncthreads();
        }
    }
    const int cbase = half * 256;
    float h = (half == 0) ? b1[row] : 0.f;
    #pragma unroll 8
    for (int l = 0; l < 256; l++)
        h += ev[cbase + l] * W1[(size_t)(cbase + l) * KK + row];
    hpart[tid] = h;
    __syncthreads();
    float term = 0.f;
    if (half == 0) {
        float hv = fmaxf(hpart[row] + hpart[row + 512], 0.f);
        term = hv * W2[row];
    }
    for (int off = 32; off; off >>= 1) term += __shfl_down(term, off);
    if ((tid & 63) == 0) red[tid >> 6] = term;
    __syncthreads();
    if (tid == 0) {
        float sc = 0.f;
        #pragma unroll
        for (int x = 0; x < 16; x++) sc += red[x];
        sc += b2[0];
        out[pair] = 1.f / (1.f + expf(-sc));
        out[NPAIR + pair] = (pair & 1) ? 0.f : 1.f;
    }
}

extern "C" void kernel_launch(void* const* d_in, const int* in_sizes, int n_in,
                              void* d_out, int out_size, void* d_ws, size_t ws_size,
                              hipStream_t stream) {
    (void)in_sizes; (void)n_in; (void)out_size; (void)ws_size;
    const float* rt    = (const float*)d_in[0];
    const float* cents = (const float*)d_in[1];
    const float* attn  = (const float*)d_in[2];
    const float* sas   = (const float*)d_in[3];
    const int* num_rt  = (const int*)d_in[4];
    const int* anc     = (const int*)d_in[5];
    const int* pos     = (const int*)d_in[6];
    const int* neg     = (const int*)d_in[7];
    const float* Win   = (const float*)d_in[8];
    const float* bin   = (const float*)d_in[9];
    const float* W1    = (const float*)d_in[10];
    const float* b1    = (const float*)d_in[11];
    const float* W2    = (const float*)d_in[12];
    const float* b2    = (const float*)d_in[13];

    float* ws = (float*)d_ws;
    _Float16* feath = (_Float16*)ws;
    _Float16* featl = (_Float16*)(ws + 4194304);
    float* normF = ws + 8388608;
    float* centk = ws + 8421376;
    float* sbuf  = ws + 8552448;
    int* topidx  = (int*)(ws + 8617984);
    int* neffp   = (int*)(ws + 8650752);
    int* corr    = (int*)(ws + 8650816);
    unsigned* gmask = (unsigned*)(ws + 8716352);
    float* partv = (float*)(ws + 8716352);
    int*   partl = (int*)(ws + 8716352 + 262144);
    float* partd = (float*)(ws + 8716352 + 524288);
    _Float16* wth = (_Float16*)(ws + 8716352 + 786432);
    _Float16* wtl = (_Float16*)(ws + 8716352 + 819200);
    float* out = (float*)d_out;

    wtrans_kernel<<<dim3(4, 4), 256, 0, stream>>>(Win, wth, wtl);
    sel_kernel<<<64, 512, 0, stream>>>(attn, cents, sas, num_rt, topidx, neffp, centk);
    feat_mfma<<<dim3(256, 2), 256, 0, stream>>>(rt, topidx, wth, wtl, bin, feath, featl);
    norm_kernel<<<8192, 256, 0, stream>>>(feath, featl, normF);
    argmin_mfma<<<dim3(4, 4, 64), 512, 0, stream>>>(feath, featl, normF, anc, pos, neg, partv, partl, partd);
    argmin_fin<<<256, 256, 0, stream>>>(partv, partl, partd, normF, anc, pos, neg, corr, sbuf);
    geo_kernel<<<dim3(2, 4, 128), 256, 0, stream>>>(centk, corr, neffp, anc, pos, neg, gmask);
    power_kernel<<<128, 1024, 0, stream>>>(gmask, sbuf, W1, b1, W2, b2, out);
}

// Round 9
// 377.013 us; speedup vs baseline: 1.0252x; 1.0252x over previous
//
#include <hip/hip_runtime.h>
#include <cstddef>

#define BB 64
#define NN 1024
#define CC 256
#define KK 512
#define TT 64
#define NPAIR 128

typedef _Float16 h8 __attribute__((ext_vector_type(8)));
typedef _Float16 h4 __attribute__((ext_vector_type(4)));
typedef float f4 __attribute__((ext_vector_type(4)));

// async global->LDS, 16B per lane; LDS dest = wave-uniform base + lane*16
typedef __attribute__((address_space(1))) const void GV;
typedef __attribute__((address_space(3))) void LV;
#define GLDS16(g, s) __builtin_amdgcn_global_load_lds((GV*)(const void*)(g), (LV*)(void*)(s), 16, 0, 0)

// ---------------- ws layout (float words) ----------------
// feath   : 0          size 4194304  (8388608 f16: 32768 x 256 hi)
// featl   : 4194304    size 4194304  (lo plane)
// normF   : 8388608    size 32768
// centk   : 8421376    size B*K*4   = 131072   (x,y,z,|c|^2)
// sbuf    : 8552448    size 65536   (T*2*K)
// topidx  : 8617984    size 32768   (int)
// neff    : 8650752    size 64      (int)
// corr    : 8650816    size 65536   (int)
// gmask   : 8716352    size NPAIR*K*16 = 1048576 (uint)
//   aliased into gmask region (all consumed before geo_kernel overwrites):
//   partv = +0 (262144), partl = +262144, partd = +524288
//   wth   = +786432 (32768 words = 65536 f16), wtl = +819200
// total 9764928 words = 39.06 MB

// ===================== stage 0: W_in transpose + f16 split =====================
__global__ __launch_bounds__(256) void wtrans_kernel(
    const float* __restrict__ Win, _Float16* __restrict__ wth, _Float16* __restrict__ wtl)
{
    __shared__ float t[64][65];
    const int k0 = blockIdx.x * 64, n0 = blockIdx.y * 64;
    const int tid = threadIdx.x;
    const int c = tid & 63, r0 = tid >> 6;
    for (int r = r0; r < 64; r += 4)
        t[r][c] = Win[(size_t)(k0 + r) * CC + n0 + c];
    __syncthreads();
    for (int r = r0; r < 64; r += 4) {
        float x = t[c][r];                     // x = Win[k0+c][n0+r]
        _Float16 h = (_Float16)x;
        size_t o = (size_t)(n0 + r) * CC + k0 + c;
        wth[o] = h;
        wtl[o] = (_Float16)(x - (float)h);
    }
}

// ===================== stage 1: selection =====================
__global__ __launch_bounds__(512) void sel_kernel(
    const float* __restrict__ attn, const float* __restrict__ cents,
    const float* __restrict__ sas, const int* __restrict__ num_rt,
    int* __restrict__ topidx, int* __restrict__ neff, float* __restrict__ centk)
{
    __shared__ unsigned long long keys[1024];
    const int b = blockIdx.x, tid = threadIdx.x;
    const int nr = num_rt[b];
    for (int i = tid; i < 1024; i += 512) {
        float a = (i < nr) ? attn[b * NN + i] : -1e9f;
        unsigned u = __float_as_uint(a);
        u = (u & 0x80000000u) ? ~u : (u | 0x80000000u);
        keys[i] = ((unsigned long long)u << 32) | (unsigned)(0xFFFFFFFFu - (unsigned)i);
    }
    __syncthreads();
    for (int k = 2; k <= 1024; k <<= 1) {
        for (int j = k >> 1; j > 0; j >>= 1) {
            int i = ((tid & ~(j - 1)) << 1) | (tid & (j - 1));
            int p = i | j;
            unsigned long long a = keys[i], c = keys[p];
            bool up = (i & k) == 0;
            if (up ? (a < c) : (a > c)) { keys[i] = c; keys[p] = a; }
            __syncthreads();
        }
    }
    {
        unsigned long long key = keys[tid];
        int idx = (int)(~(unsigned)key);
        float x = cents[(b * NN + idx) * 3 + 0];
        float y = cents[(b * NN + idx) * 3 + 1];
        float z = cents[(b * NN + idx) * 3 + 2];
        if (idx < nr) {
            float sc = sas[b * 4 + 3];
            x = x * sc + sas[b * 4 + 0];
            y = y * sc + sas[b * 4 + 1];
            z = z * sc + sas[b * 4 + 2];
        }
        float nc = x * x + y * y + z * z;
        ((float4*)centk)[b * KK + tid] = make_float4(x, y, z, nc);
        topidx[b * KK + tid] = idx;
    }
    if (tid == 0) neff[b] = (nr < KK) ? nr : KK;
}

// ===================== stage 2: feat = rt_k @ W_in + b_in via split-f16 MFMA ====
// waves 0,1: A rows load+split (f32 source); waves 2,3: async-stage Bh/Bl
__global__ __launch_bounds__(256) void feat_mfma(
    const float* __restrict__ rt, const int* __restrict__ topidx,
    const _Float16* __restrict__ wth, const _Float16* __restrict__ wtl,
    const float* __restrict__ bin,
    _Float16* __restrict__ feath, _Float16* __restrict__ featl)
{
    const int mtile = blockIdx.x, nt = blockIdx.y;
    __shared__ _Float16 Ah[128][32], Al[128][32], Bh[128][32], Bl[128][32];
    __shared__ int tix[128];
    const int tid = threadIdx.x;
    const int w = tid >> 6, lane = tid & 63;
    const int quad = lane >> 4, l16 = lane & 15;
    const int wm = (w >> 1) * 64, wl = (w & 1) * 64;
    const int b = mtile >> 2;
    if (tid < 128) tix[tid] = topidx[mtile * 128 + tid];
    __syncthreads();
    const float* arow = (tid < 128) ? rt + ((size_t)b * NN + tix[tid]) * CC : rt;
    const _Float16* bplane = (w == 2) ? wth : wtl;
    _Float16* bsh = (w == 2) ? &Bh[0][0] : &Bl[0][0];
    const int rowi = lane >> 2, chunk = lane & 3;

    f4 acc[4][4];
    #pragma unroll
    for (int i = 0; i < 4; i++)
        #pragma unroll
        for (int j = 0; j < 4; j++)
            acc[i][j] = (f4){0.f, 0.f, 0.f, 0.f};

    for (int k0 = 0; k0 < CC; k0 += 32) {
        __syncthreads();
        if (w < 2) {
            const float4* src = (const float4*)(arow + k0);
            #pragma unroll
            for (int c = 0; c < 4; c++) {
                float4 p = src[2 * c], q2 = src[2 * c + 1];
                float xv[8] = {p.x, p.y, p.z, p.w, q2.x, q2.y, q2.z, q2.w};
                h8 hv, lv;
                #pragma unroll
                for (int j = 0; j < 8; j++) {
                    _Float16 h = (_Float16)xv[j];
                    hv[j] = h;
                    lv[j] = (_Float16)(xv[j] - (float)h);
                }
                *(h8*)&Ah[tid][c * 8] = hv;
                *(h8*)&Al[tid][c * 8] = lv;
            }
        } else {
            #pragma unroll
            for (int j = 0; j < 8; j++) {
                int row = j * 16 + rowi;
                const _Float16* ga = bplane + (size_t)(nt * 128 + row) * CC + k0 + chunk * 8;
                GLDS16(ga, bsh + j * 512);
            }
        }
        __syncthreads();
        h8 afh[4], afl[4], bfh[4], bfl[4];
        #pragma unroll
        for (int i = 0; i < 4; i++) {
            int ra = wm + i * 16 + l16;
            int rb = wl + i * 16 + l16;
            afh[i] = *(const h8*)&Ah[ra][quad * 8];
            afl[i] = *(const h8*)&Al[ra][quad * 8];
            bfh[i] = *(const h8*)&Bh[rb][quad * 8];
            bfl[i] = *(const h8*)&Bl[rb][quad * 8];
        }
        #pragma unroll
        for (int i = 0; i < 4; i++)
            #pragma unroll
            for (int j = 0; j < 4; j++) {
                acc[i][j] = __builtin_amdgcn_mfma_f32_16x16x32_f16(afh[i], bfh[j], acc[i][j], 0, 0, 0);
                acc[i][j] = __builtin_amdgcn_mfma_f32_16x16x32_f16(afh[i], bfl[j], acc[i][j], 0, 0, 0);
                acc[i][j] = __builtin_amdgcn_mfma_f32_16x16x32_f16(afl[i], bfh[j], acc[i][j], 0, 0, 0);
            }
    }
    #pragma unroll
    for (int j = 0; j < 4; j++) {
        int col = wl + j * 16 + l16;
        float bj = bin[nt * 128 + col];
        #pragma unroll
        for (int i = 0; i < 4; i++)
            #pragma unroll
            for (int r = 0; r < 4; r++) {
                int row = wm + i * 16 + quad * 4 + r;
                float v = acc[i][j][r] + bj;
                _Float16 h = (_Float16)v;
                size_t o = (size_t)(mtile * 128 + row) * CC + nt * 128 + col;
                feath[o] = h;
                featl[o] = (_Float16)(v - (float)h);
            }
    }
}

// ===================== stage 2b: row norms from hi/lo =====================
__global__ __launch_bounds__(256) void norm_kernel(
    const _Float16* __restrict__ feath, const _Float16* __restrict__ featl,
    float* __restrict__ normF)
{
    int r = blockIdx.x * 4 + (threadIdx.x >> 6);
    int lane = threadIdx.x & 63;
    h4 hv = ((const h4*)(feath + (size_t)r * CC))[lane];
    h4 lv = ((const h4*)(featl + (size_t)r * CC))[lane];
    float s = 0.f;
    #pragma unroll
    for (int j = 0; j < 4; j++) {
        float x = (float)hv[j] + (float)lv[j];
        s += x * x;
    }
    for (int off = 32; off; off >>= 1) s += __shfl_down(s, off);
    if (lane == 0) normF[r] = s;
}

// ===================== stage 3a: fd argmin via split-f16 MFMA =====================
// r7 structure (256 thr, grid 4 lt x 4 kt x 128 pr) + double-buffered async
// staging: prefetch step s+1 into alternate 32KB buffer during compute of s;
// the next barrier's vmcnt drain lands one full compute phase after issue.
__global__ __launch_bounds__(256) void argmin_mfma(
    const _Float16* __restrict__ feath, const _Float16* __restrict__ featl,
    const float* __restrict__ normF,
    const int* __restrict__ anc, const int* __restrict__ pos, const int* __restrict__ neg,
    float* __restrict__ partv, int* __restrict__ partl, float* __restrict__ partd)
{
    const int lt = blockIdx.x, kt = blockIdx.y, pr = blockIdx.z;
    const int t = pr >> 1, nn2 = pr & 1;
    const int a = anc[t];
    const int bb = nn2 ? neg[t] : pos[t];
    const size_t Abase = ((size_t)a * KK + kt * 128) * CC;
    const size_t Bbase = ((size_t)bb * KK + lt * 128) * CC;
    __shared__ _Float16 smem[2][4][4096];   // [buf][plane: Ah,Al,Bh,Bl][128*32]
    __shared__ float rdv[128][2];
    __shared__ int   rdl[128][2];
    __shared__ float rdd[128][2];
    const int tid = threadIdx.x;
    const int w = tid >> 6, lane = tid & 63;
    const int quad = lane >> 4, l16 = lane & 15;
    const int wm = (w >> 1) * 64, wl = (w & 1) * 64;
    const int rowi = lane >> 2, chunk = lane & 3;
    const _Float16* gplane = (w == 0) ? feath + Abase : (w == 1) ? featl + Abase
                           : (w == 2) ? feath + Bbase : featl + Bbase;
    const _Float16* grow = gplane + (size_t)rowi * CC + chunk * 8;

    // prefetch k-step 0 into buffer 0 (each wave owns its plane)
    #pragma unroll
    for (int j = 0; j < 8; j++)
        GLDS16(grow + (size_t)(j * 16) * CC, &smem[0][w][j * 512]);

    f4 acc[4][4];
    #pragma unroll
    for (int i = 0; i < 4; i++)
        #pragma unroll
        for (int j = 0; j < 4; j++)
            acc[i][j] = (f4){0.f, 0.f, 0.f, 0.f};

    for (int step = 0; step < 8; step++) {
        const int cur = step & 1;
        __syncthreads();   // vmcnt drain: buf[cur] loads landed; buf[cur^1] free
        if (step < 7) {
            const int k0n = (step + 1) * 32;
            #pragma unroll
            for (int j = 0; j < 8; j++)
                GLDS16(grow + (size_t)(j * 16) * CC + k0n, &smem[cur ^ 1][w][j * 512]);
        }
        const _Float16* Ah = smem[cur][0];
        const _Float16* Al = smem[cur][1];
        const _Float16* Bh = smem[cur][2];
        const _Float16* Bl = smem[cur][3];
        h8 afh[4], afl[4], bfh[4], bfl[4];
        #pragma unroll
        for (int i = 0; i < 4; i++) {
            int ra = wm + i * 16 + l16;
            int rb = wl + i * 16 + l16;
            afh[i] = *(const h8*)&Ah[ra * 32 + quad * 8];
            afl[i] = *(const h8*)&Al[ra * 32 + quad * 8];
            bfh[i] = *(const h8*)&Bh[rb * 32 + quad * 8];
            bfl[i] = *(const h8*)&Bl[rb * 32 + quad * 8];
        }
        #pragma unroll
        for (int i = 0; i < 4; i++)
            #pragma unroll
            for (int j = 0; j < 4; j++) {
                acc[i][j] = __builtin_amdgcn_mfma_f32_16x16x32_f16(afh[i], bfh[j], acc[i][j], 0, 0, 0);
                acc[i][j] = __builtin_amdgcn_mfma_f32_16x16x32_f16(afh[i], bfl[j], acc[i][j], 0, 0, 0);
                acc[i][j] = __builtin_amdgcn_mfma_f32_16x16x32_f16(afl[i], bfh[j], acc[i][j], 0, 0, 0);
            }
    }
    float nbj[4];
    #pragma unroll
    for (int j = 0; j < 4; j++)
        nbj[j] = normF[(size_t)bb * KK + lt * 128 + wl + j * 16 + l16];
    #pragma unroll
    for (int i = 0; i < 4; i++) {
        #pragma unroll
        for (int r = 0; r < 4; r++) {
            float bv = INFINITY; int bl = 0; float bd = 0.f;
            #pragma unroll
            for (int j = 0; j < 4; j++) {
                float d = acc[i][j][r];
                float v = nbj[j] - 2.f * d;
                int l = lt * 128 + wl + j * 16 + l16;
                if (v < bv) { bv = v; bl = l; bd = d; }
            }
            #pragma unroll
            for (int off = 1; off < 16; off <<= 1) {
                float ov = __shfl_xor(bv, off);
                int   ol = __shfl_xor(bl, off);
                float od = __shfl_xor(bd, off);
                if (ov < bv || (ov == bv && ol < bl)) { bv = ov; bl = ol; bd = od; }
            }
            if (l16 == 0) {
                int row = wm + i * 16 + quad * 4 + r;
                rdv[row][w & 1] = bv;
                rdl[row][w & 1] = bl;
                rdd[row][w & 1] = bd;
            }
        }
    }
    __syncthreads();
    if (tid < 128) {
        float bv = rdv[tid][0]; int bl = rdl[tid][0]; float bd = rdd[tid][0];
        float v1 = rdv[tid][1]; int l1 = rdl[tid][1];
        if (v1 < bv || (v1 == bv && l1 < bl)) { bv = v1; bl = l1; bd = rdd[tid][1]; }
        size_t idx = (((size_t)pr * 4 + kt) * 128 + tid) * 4 + lt;
        partv[idx] = bv; partl[idx] = bl; partd[idx] = bd;
    }
}

// ===================== stage 3b: merge l-tiles, emit corr + s =====================
__global__ __launch_bounds__(256) void argmin_fin(
    const float* __restrict__ partv, const int* __restrict__ partl,
    const float* __restrict__ partd, const float* __restrict__ normF,
    const int* __restrict__ anc, const int* __restrict__ pos, const int* __restrict__ neg,
    int* __restrict__ corr, float* __restrict__ sbuf)
{
    int g = blockIdx.x * 256 + threadIdx.x;
    int pr = g >> 9, kg = g & 511;
    int t = pr >> 1, nn2 = pr & 1;
    int a = anc[t];
    int bb = nn2 ? neg[t] : pos[t];
    size_t base = (size_t)g * 4;
    float bv = partv[base]; int bl = partl[base]; float bd = partd[base];
    #pragma unroll
    for (int lt = 1; lt < 4; lt++) {
        float v = partv[base + lt]; int l = partl[base + lt];
        if (v < bv || (v == bv && l < bl)) { bv = v; bl = l; bd = partd[base + lt]; }
    }
    float na = normF[(size_t)a * KK + kg];
    float nb = normF[(size_t)bb * KK + bl];
    float cosv = bd / (sqrtf(na) * sqrtf(nb) + 1e-8f);
    corr[g] = bl;
    sbuf[g] = fmaxf(cosv, 0.f);
}

// ===================== stage 4: geo bitmask =====================
// grid (2 kt, 4 lt, 128 pair) = 1024 blocks -> 4 blocks/CU, 16 waves/CU
__global__ __launch_bounds__(256) void geo_kernel(
    const float* __restrict__ centk, const int* __restrict__ corr,
    const int* __restrict__ neff,
    const int* __restrict__ anc, const int* __restrict__ pos, const int* __restrict__ neg,
    unsigned* __restrict__ gmask)
{
    const int kt = blockIdx.x;          // 0..1 (256 rows)
    const int lt = blockIdx.y;          // 0..3 (128 cols)
    const int pair = blockIdx.z;        // 0..127
    const int t = pair >> 1, nn2 = pair & 1;
    const int a = anc[t];
    const int bb2 = (nn2 == 0) ? pos[t] : neg[t];
    const int nea = neff[a], neb = neff[bb2];
    __shared__ __align__(16) float4 ca[512], cq[512];
    for (int i = threadIdx.x; i < KK; i += 256) {
        ca[i] = ((const float4*)centk)[a * KK + i];
        int c = corr[pair * KK + i];
        cq[i] = ((const float4*)centk)[bb2 * KK + c];
    }
    __syncthreads();
    const int k = kt * 256 + threadIdx.x;
    float4 pk = ca[k], qk = cq[k];
    bool rowm = k < nea;
    unsigned* outp = gmask + ((size_t)pair * KK + k) * 16 + lt * 4;
    for (int w = 0; w < 4; w++) {
        unsigned word = 0;
        #pragma unroll
        for (int bi = 0; bi < 32; bi++) {
            int l = lt * 128 + w * 32 + bi;
            float4 pl = ca[l], ql = cq[l];
            float dp2 = pk.w + pl.w - 2.f * (pk.x * pl.x + pk.y * pl.y + pk.z * pl.z);
            float dp = sqrtf(fmaxf(dp2, 0.f) + 1e-12f);
            float dq2 = qk.w + ql.w - 2.f * (qk.x * ql.x + qk.y * ql.y + qk.z * ql.z);
            float dq = sqrtf(fmaxf(dq2, 0.f) + 1e-12f);
            bool g = (fabsf(dp - dq) < 0.5f) && rowm && (l < neb) && (l != k);
            word |= (g ? (1u << bi) : 0u);
        }
        outp[w] = word;
    }
}

// ===================== stage 5: power iteration + sort + MLP =====================
__global__ __launch_bounds__(1024, 4) void power_kernel(
    const unsigned* __restrict__ gmask, const float* __restrict__ sbuf,
    const float* __restrict__ W1, const float* __restrict__ b1,
    const float* __restrict__ W2, const float* __restrict__ b2,
    float* __restrict__ out)
{
    const int pair = blockIdx.x;
    const int tid = threadIdx.x;
    const int row = tid & 511;
    const int half = tid >> 9;
    __shared__ __align__(16) float u[512];
    __shared__ float T[64][257];
    __shared__ float pacc[1024];
    __shared__ float red[16];
    __shared__ float ev[512];
    __shared__ float hpart[1024];
    unsigned m[8];
    const unsigned* g = gmask + ((size_t)pair * KK + row) * 16 + half * 8;
    #pragma unroll
    for (int w = 0; w < 8; w++) m[w] = g[w];
    const float s = sbuf[pair * KK + row];
    const int bp = tid & 63;
    const int vh = tid >> 6;
    const int GV_[16] = {0,1,3,2,6,7,5,4,12,13,15,14,10,11,9,8};
    const int GB[15] = {0,1,0,2,0,1,0,3,0,1,0,2,0,1,0};
    const float GS[15] = {1.f,1.f,-1.f,1.f,1.f,-1.f,-1.f,1.f,1.f,1.f,-1.f,-1.f,1.f,-1.f,-1.f};
    float v = 0.044194173824159216f;   // 1/sqrt(512)
    if (half == 0) u[row] = s * v;
    __syncthreads();
    for (int it = 0; it < 20; it++) {
        {
            float4 ulo = *(const float4*)&u[bp * 8];
            float4 uhi = *(const float4*)&u[bp * 8 + 4];
            float ul[4] = {ulo.x, ulo.y, ulo.z, ulo.w};
            float H = 0.f;
            H += (float)((vh >> 0) & 1) * uhi.x;
            H += (float)((vh >> 1) & 1) * uhi.y;
            H += (float)((vh >> 2) & 1) * uhi.z;
            H += (float)((vh >> 3) & 1) * uhi.w;
            float L = 0.f;
            T[bp][vh * 16 + 0] = H;
            #pragma unroll
            for (int k = 1; k < 16; k++) {
                L += GS[k - 1] * ul[GB[k - 1]];
                T[bp][vh * 16 + GV_[k]] = H + L;
            }
        }
        __syncthreads();
        float a0 = 0.f, a1 = 0.f, a2 = 0.f, a3 = 0.f;
        #pragma unroll
        for (int w = 0; w < 8; w++) {
            unsigned mw = m[w];
            const int p0 = half * 32 + w * 4;
            a0 += T[p0 + 0][mw & 255u];
            a1 += T[p0 + 1][(mw >> 8) & 255u];
            a2 += T[p0 + 2][(mw >> 16) & 255u];
            a3 += T[p0 + 3][mw >> 24];
        }
        pacc[tid] = (a0 + a1) + (a2 + a3);
        __syncthreads();
        float wk = s * (pacc[row] + pacc[row + 512]);
        float t2 = wk * wk;
        for (int off = 32; off; off >>= 1) t2 += __shfl_down(t2, off);
        if ((tid & 63) == 0) red[tid >> 6] = t2;
        __syncthreads();
        float tot = 0.f;
        #pragma unroll
        for (int x = 0; x < 16; x++) tot += red[x];
        tot *= 0.5f;
        v = wk / (sqrtf(tot) + 1e-8f);
        if (half == 0) u[row] = s * v;
        __syncthreads();
    }
    if (half == 0) ev[row] = v;
    __syncthreads();
    for (int kk = 2; kk <= 512; kk <<= 1) {
        for (int j = kk >> 1; j; j >>= 1) {
            if (tid < 256) {
                int i = ((tid & ~(j - 1)) << 1) | (tid & (j - 1));
                int p = i | j;
                float x = ev[i], y = ev[p];
                bool up = (i & kk) == 0;
                if (up ? (x < y) : (x > y)) { ev[i] = y; ev[p] = x; }
            }
            __syncthreads();
        }
    }
    const int cbase = half * 256;
    float h = (half == 0) ? b1[row] : 0.f;
    #pragma unroll 8
    for (int l = 0; l < 256; l++)
        h += ev[cbase + l] * W1[(size_t)(cbase + l) * KK + row];
    hpart[tid] = h;
    __syncthreads();
    float term = 0.f;
    if (half == 0) {
        float hv = fmaxf(hpart[row] + hpart[row + 512], 0.f);
        term = hv * W2[row];
    }
    for (int off = 32; off; off >>= 1) term += __shfl_down(term, off);
    if ((tid & 63) == 0) red[tid >> 6] = term;
    __syncthreads();
    if (tid == 0) {
        float sc = 0.f;
        #pragma unroll
        for (int x = 0; x < 16; x++) sc += red[x];
        sc += b2[0];
        out[pair] = 1.f / (1.f + expf(-sc));
        out[NPAIR + pair] = (pair & 1) ? 0.f : 1.f;
    }
}

extern "C" void kernel_launch(void* const* d_in, const int* in_sizes, int n_in,
                              void* d_out, int out_size, void* d_ws, size_t ws_size,
                              hipStream_t stream) {
    (void)in_sizes; (void)n_in; (void)out_size; (void)ws_size;
    const float* rt    = (const float*)d_in[0];
    const float* cents = (const float*)d_in[1];
    const float* attn  = (const float*)d_in[2];
    const float* sas   = (const float*)d_in[3];
    const int* num_rt  = (const int*)d_in[4];
    const int* anc     = (const int*)d_in[5];
    const int* pos     = (const int*)d_in[6];
    const int* neg     = (const int*)d_in[7];
    const float* Win   = (const float*)d_in[8];
    const float* bin   = (const float*)d_in[9];
    const float* W1    = (const float*)d_in[10];
    const float* b1    = (const float*)d_in[11];
    const float* W2    = (const float*)d_in[12];
    const float* b2    = (const float*)d_in[13];

    float* ws = (float*)d_ws;
    _Float16* feath = (_Float16*)ws;
    _Float16* featl = (_Float16*)(ws + 4194304);
    float* normF = ws + 8388608;
    float* centk = ws + 8421376;
    float* sbuf  = ws + 8552448;
    int* topidx  = (int*)(ws + 8617984);
    int* neffp   = (int*)(ws + 8650752);
    int* corr    = (int*)(ws + 8650816);
    unsigned* gmask = (unsigned*)(ws + 8716352);
    float* partv = (float*)(ws + 8716352);
    int*   partl = (int*)(ws + 8716352 + 262144);
    float* partd = (float*)(ws + 8716352 + 524288);
    _Float16* wth = (_Float16*)(ws + 8716352 + 786432);
    _Float16* wtl = (_Float16*)(ws + 8716352 + 819200);
    float* out = (float*)d_out;

    wtrans_kernel<<<dim3(4, 4), 256, 0, stream>>>(Win, wth, wtl);
    sel_kernel<<<64, 512, 0, stream>>>(attn, cents, sas, num_rt, topidx, neffp, centk);
    feat_mfma<<<dim3(256, 2), 256, 0, stream>>>(rt, topidx, wth, wtl, bin, feath, featl);
    norm_kernel<<<8192, 256, 0, stream>>>(feath, featl, normF);
    argmin_mfma<<<dim3(4, 4, 128), 256, 0, stream>>>(feath, featl, normF, anc, pos, neg, partv, partl, partd);
    argmin_fin<<<256, 256, 0, stream>>>(partv, partl, partd, normF, anc, pos, neg, corr, sbuf);
    geo_kernel<<<dim3(2, 4, 128), 256, 0, stream>>>(centk, corr, neffp, anc, pos, neg, gmask);
    power_kernel<<<128, 1024, 0, stream>>>(gmask, sbuf, W1, b1, W2, b2, out);
}

// Round 10
// 371.982 us; speedup vs baseline: 1.0391x; 1.0135x over previous
//
#include <hip/hip_runtime.h>
#include <cstddef>

#define BB 64
#define NN 1024
#define CC 256
#define KK 512
#define TT 64
#define NPAIR 128

typedef _Float16 h8 __attribute__((ext_vector_type(8)));
typedef _Float16 h4 __attribute__((ext_vector_type(4)));
typedef float f4 __attribute__((ext_vector_type(4)));

// async global->LDS, 16B per lane; LDS dest = wave-uniform base + lane*16
typedef __attribute__((address_space(1))) const void GV;
typedef __attribute__((address_space(3))) void LV;
#define GLDS16(g, s) __builtin_amdgcn_global_load_lds((GV*)(const void*)(g), (LV*)(void*)(s), 16, 0, 0)

// ---------------- ws layout (float words) ----------------
// feath   : 0          size 4194304  (8388608 f16: 32768 x 256 hi)
// featl   : 4194304    size 4194304  (lo plane)
// normF   : 8388608    size 32768
// centk   : 8421376    size B*K*4   = 131072   (x,y,z,|c|^2)
// sbuf    : 8552448    size 65536   (T*2*K)
// topidx  : 8617984    size 32768   (int)
// neff    : 8650752    size 64      (int)
// gmask   : 8716352    size NPAIR*K*16 = 1048576 (uint)
//   wth/wtl alias gmask top (+786432 / +819200) - consumed by feat before geo
// partv   : 9764928    size 262144   (moved past gmask: geo reads these while
// partl   : 10027072   size 262144    writing gmask - must not alias)
// partd   : 10289216   size 262144
// total 10551360 words = 42.2 MB

// ===================== stage 0: W_in transpose + f16 split =====================
__global__ __launch_bounds__(256) void wtrans_kernel(
    const float* __restrict__ Win, _Float16* __restrict__ wth, _Float16* __restrict__ wtl)
{
    __shared__ float t[64][65];
    const int k0 = blockIdx.x * 64, n0 = blockIdx.y * 64;
    const int tid = threadIdx.x;
    const int c = tid & 63, r0 = tid >> 6;
    for (int r = r0; r < 64; r += 4)
        t[r][c] = Win[(size_t)(k0 + r) * CC + n0 + c];
    __syncthreads();
    for (int r = r0; r < 64; r += 4) {
        float x = t[c][r];                     // x = Win[k0+c][n0+r]
        _Float16 h = (_Float16)x;
        size_t o = (size_t)(n0 + r) * CC + k0 + c;
        wth[o] = h;
        wtl[o] = (_Float16)(x - (float)h);
    }
}

// ===================== stage 1: selection =====================
__global__ __launch_bounds__(512) void sel_kernel(
    const float* __restrict__ attn, const float* __restrict__ cents,
    const float* __restrict__ sas, const int* __restrict__ num_rt,
    int* __restrict__ topidx, int* __restrict__ neff, float* __restrict__ centk)
{
    __shared__ unsigned long long keys[1024];
    const int b = blockIdx.x, tid = threadIdx.x;
    const int nr = num_rt[b];
    for (int i = tid; i < 1024; i += 512) {
        float a = (i < nr) ? attn[b * NN + i] : -1e9f;
        unsigned u = __float_as_uint(a);
        u = (u & 0x80000000u) ? ~u : (u | 0x80000000u);
        keys[i] = ((unsigned long long)u << 32) | (unsigned)(0xFFFFFFFFu - (unsigned)i);
    }
    __syncthreads();
    for (int k = 2; k <= 1024; k <<= 1) {
        for (int j = k >> 1; j > 0; j >>= 1) {
            int i = ((tid & ~(j - 1)) << 1) | (tid & (j - 1));
            int p = i | j;
            unsigned long long a = keys[i], c = keys[p];
            bool up = (i & k) == 0;
            if (up ? (a < c) : (a > c)) { keys[i] = c; keys[p] = a; }
            __syncthreads();
        }
    }
    {
        unsigned long long key = keys[tid];
        int idx = (int)(~(unsigned)key);
        float x = cents[(b * NN + idx) * 3 + 0];
        float y = cents[(b * NN + idx) * 3 + 1];
        float z = cents[(b * NN + idx) * 3 + 2];
        if (idx < nr) {
            float sc = sas[b * 4 + 3];
            x = x * sc + sas[b * 4 + 0];
            y = y * sc + sas[b * 4 + 1];
            z = z * sc + sas[b * 4 + 2];
        }
        float nc = x * x + y * y + z * z;
        ((float4*)centk)[b * KK + tid] = make_float4(x, y, z, nc);
        topidx[b * KK + tid] = idx;
    }
    if (tid == 0) neff[b] = (nr < KK) ? nr : KK;
}

// ===================== stage 2: feat = rt_k @ W_in + b_in via split-f16 MFMA ====
// Balanced staging: every thread converts one row-half of A (2 float4 -> 2 h8
// per plane); all 4 waves split the 16 async B wave-loads (4 each).
__global__ __launch_bounds__(256) void feat_mfma(
    const float* __restrict__ rt, const int* __restrict__ topidx,
    const _Float16* __restrict__ wth, const _Float16* __restrict__ wtl,
    const float* __restrict__ bin,
    _Float16* __restrict__ feath, _Float16* __restrict__ featl)
{
    const int mtile = blockIdx.x, nt = blockIdx.y;
    __shared__ _Float16 Ah[128][32], Al[128][32], Bh[128][32], Bl[128][32];
    __shared__ int tix[128];
    const int tid = threadIdx.x;
    const int w = tid >> 6, lane = tid & 63;
    const int quad = lane >> 4, l16 = lane & 15;
    const int wm = (w >> 1) * 64, wl = (w & 1) * 64;
    const int b = mtile >> 2;
    if (tid < 128) tix[tid] = topidx[mtile * 128 + tid];
    __syncthreads();
    const int arow_i = tid >> 1;              // A row this thread converts
    const int aseg = (tid & 1) * 16;          // 16-col half of that row
    const float* arow = rt + ((size_t)b * NN + tix[arow_i]) * CC + aseg;
    _Float16* bsh = (w < 2) ? &Bh[0][0] : &Bl[0][0];
    const _Float16* bplane = (w < 2) ? wth : wtl;
    const int rowi = lane >> 2, chunk = lane & 3;

    f4 acc[4][4];
    #pragma unroll
    for (int i = 0; i < 4; i++)
        #pragma unroll
        for (int j = 0; j < 4; j++)
            acc[i][j] = (f4){0.f, 0.f, 0.f, 0.f};

    for (int k0 = 0; k0 < CC; k0 += 32) {
        __syncthreads();
        // B async first (4 wave-loads per wave)
        #pragma unroll
        for (int jj = 0; jj < 4; jj++) {
            int j = (w & 1) * 4 + jj;
            int row = j * 16 + rowi;
            GLDS16(bplane + (size_t)(nt * 128 + row) * CC + k0 + chunk * 8, bsh + j * 512);
        }
        // A convert (every thread)
        {
            const float4* src = (const float4*)(arow + k0);
            #pragma unroll
            for (int c = 0; c < 2; c++) {
                float4 p = src[2 * c], q2 = src[2 * c + 1];
                float xv[8] = {p.x, p.y, p.z, p.w, q2.x, q2.y, q2.z, q2.w};
                h8 hv, lv;
                #pragma unroll
                for (int j = 0; j < 8; j++) {
                    _Float16 h = (_Float16)xv[j];
                    hv[j] = h;
                    lv[j] = (_Float16)(xv[j] - (float)h);
                }
                *(h8*)&Ah[arow_i][aseg + c * 8] = hv;
                *(h8*)&Al[arow_i][aseg + c * 8] = lv;
            }
        }
        __syncthreads();
        h8 afh[4], afl[4], bfh[4], bfl[4];
        #pragma unroll
        for (int i = 0; i < 4; i++) {
            int ra = wm + i * 16 + l16;
            int rb = wl + i * 16 + l16;
            afh[i] = *(const h8*)&Ah[ra][quad * 8];
            afl[i] = *(const h8*)&Al[ra][quad * 8];
            bfh[i] = *(const h8*)&Bh[rb][quad * 8];
            bfl[i] = *(const h8*)&Bl[rb][quad * 8];
        }
        #pragma unroll
        for (int i = 0; i < 4; i++)
            #pragma unroll
            for (int j = 0; j < 4; j++) {
                acc[i][j] = __builtin_amdgcn_mfma_f32_16x16x32_f16(afh[i], bfh[j], acc[i][j], 0, 0, 0);
                acc[i][j] = __builtin_amdgcn_mfma_f32_16x16x32_f16(afh[i], bfl[j], acc[i][j], 0, 0, 0);
                acc[i][j] = __builtin_amdgcn_mfma_f32_16x16x32_f16(afl[i], bfh[j], acc[i][j], 0, 0, 0);
            }
    }
    #pragma unroll
    for (int j = 0; j < 4; j++) {
        int col = wl + j * 16 + l16;
        float bj = bin[nt * 128 + col];
        #pragma unroll
        for (int i = 0; i < 4; i++)
            #pragma unroll
            for (int r = 0; r < 4; r++) {
                int row = wm + i * 16 + quad * 4 + r;
                float v = acc[i][j][r] + bj;
                _Float16 h = (_Float16)v;
                size_t o = (size_t)(mtile * 128 + row) * CC + nt * 128 + col;
                feath[o] = h;
                featl[o] = (_Float16)(v - (float)h);
            }
    }
}

// ===================== stage 2b: row norms from hi/lo =====================
__global__ __launch_bounds__(256) void norm_kernel(
    const _Float16* __restrict__ feath, const _Float16* __restrict__ featl,
    float* __restrict__ normF)
{
    int r = blockIdx.x * 4 + (threadIdx.x >> 6);
    int lane = threadIdx.x & 63;
    h4 hv = ((const h4*)(feath + (size_t)r * CC))[lane];
    h4 lv = ((const h4*)(featl + (size_t)r * CC))[lane];
    float s = 0.f;
    #pragma unroll
    for (int j = 0; j < 4; j++) {
        float x = (float)hv[j] + (float)lv[j];
        s += x * x;
    }
    for (int off = 32; off; off >>= 1) s += __shfl_down(s, off);
    if (lane == 0) normF[r] = s;
}

// ===================== stage 3: fd argmin via split-f16 MFMA (r7 form) ==========
// 256 thr, grid (4 lt, 4 kt, 128 pr); fully async staging, single-buffered.
__global__ __launch_bounds__(256) void argmin_mfma(
    const _Float16* __restrict__ feath, const _Float16* __restrict__ featl,
    const float* __restrict__ normF,
    const int* __restrict__ anc, const int* __restrict__ pos, const int* __restrict__ neg,
    float* __restrict__ partv, int* __restrict__ partl, float* __restrict__ partd)
{
    const int lt = blockIdx.x, kt = blockIdx.y, pr = blockIdx.z;
    const int t = pr >> 1, nn2 = pr & 1;
    const int a = anc[t];
    const int bb = nn2 ? neg[t] : pos[t];
    const size_t Abase = ((size_t)a * KK + kt * 128) * CC;
    const size_t Bbase = ((size_t)bb * KK + lt * 128) * CC;
    __shared__ _Float16 Ah[128][32], Al[128][32], Bh[128][32], Bl[128][32];
    __shared__ float rdv[128][2];
    __shared__ int   rdl[128][2];
    __shared__ float rdd[128][2];
    const int tid = threadIdx.x;
    const int w = tid >> 6, lane = tid & 63;
    const int quad = lane >> 4, l16 = lane & 15;
    const int wm = (w >> 1) * 64, wl = (w & 1) * 64;
    const int rowi = lane >> 2, chunk = lane & 3;
    const _Float16* gplane = (w == 0) ? feath + Abase : (w == 1) ? featl + Abase
                           : (w == 2) ? feath + Bbase : featl + Bbase;
    _Float16* splane = (w == 0) ? &Ah[0][0] : (w == 1) ? &Al[0][0]
                     : (w == 2) ? &Bh[0][0] : &Bl[0][0];
    const _Float16* grow = gplane + (size_t)rowi * CC + chunk * 8;

    f4 acc[4][4];
    #pragma unroll
    for (int i = 0; i < 4; i++)
        #pragma unroll
        for (int j = 0; j < 4; j++)
            acc[i][j] = (f4){0.f, 0.f, 0.f, 0.f};

    for (int k0 = 0; k0 < CC; k0 += 32) {
        __syncthreads();
        #pragma unroll
        for (int j = 0; j < 8; j++)
            GLDS16(grow + (size_t)(j * 16) * CC + k0, splane + j * 512);
        __syncthreads();
        h8 afh[4], afl[4], bfh[4], bfl[4];
        #pragma unroll
        for (int i = 0; i < 4; i++) {
            int ra = wm + i * 16 + l16;
            int rb = wl + i * 16 + l16;
            afh[i] = *(const h8*)&Ah[ra][quad * 8];
            afl[i] = *(const h8*)&Al[ra][quad * 8];
            bfh[i] = *(const h8*)&Bh[rb][quad * 8];
            bfl[i] = *(const h8*)&Bl[rb][quad * 8];
        }
        #pragma unroll
        for (int i = 0; i < 4; i++)
            #pragma unroll
            for (int j = 0; j < 4; j++) {
                acc[i][j] = __builtin_amdgcn_mfma_f32_16x16x32_f16(afh[i], bfh[j], acc[i][j], 0, 0, 0);
                acc[i][j] = __builtin_amdgcn_mfma_f32_16x16x32_f16(afh[i], bfl[j], acc[i][j], 0, 0, 0);
                acc[i][j] = __builtin_amdgcn_mfma_f32_16x16x32_f16(afl[i], bfh[j], acc[i][j], 0, 0, 0);
            }
    }
    float nbj[4];
    #pragma unroll
    for (int j = 0; j < 4; j++)
        nbj[j] = normF[(size_t)bb * KK + lt * 128 + wl + j * 16 + l16];
    #pragma unroll
    for (int i = 0; i < 4; i++) {
        #pragma unroll
        for (int r = 0; r < 4; r++) {
            float bv = INFINITY; int bl = 0; float bd = 0.f;
            #pragma unroll
            for (int j = 0; j < 4; j++) {
                float d = acc[i][j][r];
                float v = nbj[j] - 2.f * d;
                int l = lt * 128 + wl + j * 16 + l16;
                if (v < bv) { bv = v; bl = l; bd = d; }
            }
            #pragma unroll
            for (int off = 1; off < 16; off <<= 1) {
                float ov = __shfl_xor(bv, off);
                int   ol = __shfl_xor(bl, off);
                float od = __shfl_xor(bd, off);
                if (ov < bv || (ov == bv && ol < bl)) { bv = ov; bl = ol; bd = od; }
            }
            if (l16 == 0) {
                int row = wm + i * 16 + quad * 4 + r;
                rdv[row][w & 1] = bv;
                rdl[row][w & 1] = bl;
                rdd[row][w & 1] = bd;
            }
        }
    }
    __syncthreads();
    if (tid < 128) {
        float bv = rdv[tid][0]; int bl = rdl[tid][0]; float bd = rdd[tid][0];
        float v1 = rdv[tid][1]; int l1 = rdl[tid][1];
        if (v1 < bv || (v1 == bv && l1 < bl)) { bv = v1; bl = l1; bd = rdd[tid][1]; }
        size_t idx = (((size_t)pr * 4 + kt) * 128 + tid) * 4 + lt;
        partv[idx] = bv; partl[idx] = bl; partd[idx] = bd;
    }
}

// ===================== stage 4: geo bitmask (argmin_fin fused) =====================
// grid (2 kt, 4 lt, 128 pair). Each block merges the 4 l-tile partials inline
// (corr needed for the cq gather anyway); block (0,0) also emits sbuf.
__global__ __launch_bounds__(256) void geo_kernel(
    const float* __restrict__ centk,
    const float* __restrict__ partv, const int* __restrict__ partl,
    const float* __restrict__ partd, const float* __restrict__ normF,
    const int* __restrict__ neff,
    const int* __restrict__ anc, const int* __restrict__ pos, const int* __restrict__ neg,
    float* __restrict__ sbuf, unsigned* __restrict__ gmask)
{
    const int kt = blockIdx.x;          // 0..1 (256 rows)
    const int lt4 = blockIdx.y;         // 0..3 (128 cols)
    const int pair = blockIdx.z;        // 0..127
    const int t = pair >> 1, nn2 = pair & 1;
    const int a = anc[t];
    const int bb2 = (nn2 == 0) ? pos[t] : neg[t];
    const int nea = neff[a], neb = neff[bb2];
    const bool writer = (kt == 0) && (lt4 == 0);
    __shared__ int ci[512];
    __shared__ __align__(16) float4 ca[512], cq[512];
    // fused argmin_fin: merge l-tile partials (identical tie-break order)
    for (int i = threadIdx.x; i < KK; i += 256) {
        size_t base = ((size_t)pair * KK + i) * 4;
        float bv = partv[base]; int bl = partl[base]; float bd = partd[base];
        #pragma unroll
        for (int lt = 1; lt < 4; lt++) {
            float v = partv[base + lt]; int l = partl[base + lt];
            if (v < bv || (v == bv && l < bl)) { bv = v; bl = l; bd = partd[base + lt]; }
        }
        ci[i] = bl;
        if (writer) {
            float na = normF[(size_t)a * KK + i];
            float nb = normF[(size_t)bb2 * KK + bl];
            float cosv = bd / (sqrtf(na) * sqrtf(nb) + 1e-8f);
            sbuf[pair * KK + i] = fmaxf(cosv, 0.f);
        }
    }
    __syncthreads();
    for (int i = threadIdx.x; i < KK; i += 256) {
        ca[i] = ((const float4*)centk)[a * KK + i];
        cq[i] = ((const float4*)centk)[bb2 * KK + ci[i]];
    }
    __syncthreads();
    const int k = kt * 256 + threadIdx.x;
    float4 pk = ca[k], qk = cq[k];
    bool rowm = k < nea;
    unsigned* outp = gmask + ((size_t)pair * KK + k) * 16 + lt4 * 4;
    for (int w = 0; w < 4; w++) {
        unsigned word = 0;
        #pragma unroll
        for (int bi = 0; bi < 32; bi++) {
            int l = lt4 * 128 + w * 32 + bi;
            float4 pl = ca[l], ql = cq[l];
            float dp2 = pk.w + pl.w - 2.f * (pk.x * pl.x + pk.y * pl.y + pk.z * pl.z);
            float dp = sqrtf(fmaxf(dp2, 0.f) + 1e-12f);
            float dq2 = qk.w + ql.w - 2.f * (qk.x * ql.x + qk.y * ql.y + qk.z * ql.z);
            float dq = sqrtf(fmaxf(dq2, 0.f) + 1e-12f);
            bool g = (fabsf(dp - dq) < 0.5f) && rowm && (l < neb) && (l != k);
            word |= (g ? (1u << bi) : 0u);
        }
        outp[w] = word;
    }
}

// ===================== stage 5: power iteration + sort + MLP =====================
__global__ __launch_bounds__(1024, 4) void power_kernel(
    const unsigned* __restrict__ gmask, const float* __restrict__ sbuf,
    const float* __restrict__ W1, const float* __restrict__ b1,
    const float* __restrict__ W2, const float* __restrict__ b2,
    float* __restrict__ out)
{
    const int pair = blockIdx.x;
    const int tid = threadIdx.x;
    const int row = tid & 511;
    const int half = tid >> 9;
    __shared__ __align__(16) float u[512];
    __shared__ float T[64][257];
    __shared__ float pacc[1024];
    __shared__ float red[16];
    __shared__ float ev[512];
    __shared__ float hpart[1024];
    unsigned m[8];
    const unsigned* g = gmask + ((size_t)pair * KK + row) * 16 + half * 8;
    #pragma unroll
    for (int w = 0; w < 8; w++) m[w] = g[w];
    const float s = sbuf[pair * KK + row];
    const int bp = tid & 63;
    const int vh = tid >> 6;
    const int GV_[16] = {0,1,3,2,6,7,5,4,12,13,15,14,10,11,9,8};
    const int GB[15] = {0,1,0,2,0,1,0,3,0,1,0,2,0,1,0};
    const float GS[15] = {1.f,1.f,-1.f,1.f,1.f,-1.f,-1.f,1.f,1.f,1.f,-1.f,-1.f,1.f,-1.f,-1.f};
    float v = 0.044194173824159216f;   // 1/sqrt(512)
    if (half == 0) u[row] = s * v;
    __syncthreads();
    for (int it = 0; it < 20; it++) {
        {
            float4 ulo = *(const float4*)&u[bp * 8];
            float4 uhi = *(const float4*)&u[bp * 8 + 4];
            float ul[4] = {ulo.x, ulo.y, ulo.z, ulo.w};
            float H = 0.f;
            H += (float)((vh >> 0) & 1) * uhi.x;
            H += (float)((vh >> 1) & 1) * uhi.y;
            H += (float)((vh >> 2) & 1) * uhi.z;
            H += (float)((vh >> 3) & 1) * uhi.w;
            float L = 0.f;
            T[bp][vh * 16 + 0] = H;
            #pragma unroll
            for (int k = 1; k < 16; k++) {
                L += GS[k - 1] * ul[GB[k - 1]];
                T[bp][vh * 16 + GV_[k]] = H + L;
            }
        }
        __syncthreads();
        float a0 = 0.f, a1 = 0.f, a2 = 0.f, a3 = 0.f;
        #pragma unroll
        for (int w = 0; w < 8; w++) {
            unsigned mw = m[w];
            const int p0 = half * 32 + w * 4;
            a0 += T[p0 + 0][mw & 255u];
            a1 += T[p0 + 1][(mw >> 8) & 255u];
            a2 += T[p0 + 2][(mw >> 16) & 255u];
            a3 += T[p0 + 3][mw >> 24];
        }
        pacc[tid] = (a0 + a1) + (a2 + a3);
        __syncthreads();
        float wk = s * (pacc[row] + pacc[row + 512]);
        float t2 = wk * wk;
        for (int off = 32; off; off >>= 1) t2 += __shfl_down(t2, off);
        if ((tid & 63) == 0) red[tid >> 6] = t2;
        __syncthreads();
        float tot = 0.f;
        #pragma unroll
        for (int x = 0; x < 16; x++) tot += red[x];
        tot *= 0.5f;
        v = wk / (sqrtf(tot) + 1e-8f);
        if (half == 0) u[row] = s * v;
        __syncthreads();
    }
    if (half == 0) ev[row] = v;
    __syncthreads();
    for (int kk = 2; kk <= 512; kk <<= 1) {
        for (int j = kk >> 1; j; j >>= 1) {
            if (tid < 256) {
                int i = ((tid & ~(j - 1)) << 1) | (tid & (j - 1));
                int p = i | j;
                float x = ev[i], y = ev[p];
                bool up = (i & kk) == 0;
                if (up ? (x < y) : (x > y)) { ev[i] = y; ev[p] = x; }
            }
            __syncthreads();
        }
    }
    const int cbase = half * 256;
    float h = (half == 0) ? b1[row] : 0.f;
    #pragma unroll 8
    for (int l = 0; l < 256; l++)
        h += ev[cbase + l] * W1[(size_t)(cbase + l) * KK + row];
    hpart[tid] = h;
    __syncthreads();
    float term = 0.f;
    if (half == 0) {
        float hv = fmaxf(hpart[row] + hpart[row + 512], 0.f);
        term = hv * W2[row];
    }
    for (int off = 32; off; off >>= 1) term += __shfl_down(term, off);
    if ((tid & 63) == 0) red[tid >> 6] = term;
    __syncthreads();
    if (tid == 0) {
        float sc = 0.f;
        #pragma unroll
        for (int x = 0; x < 16; x++) sc += red[x];
        sc += b2[0];
        out[pair] = 1.f / (1.f + expf(-sc));
        out[NPAIR + pair] = (pair & 1) ? 0.f : 1.f;
    }
}

extern "C" void kernel_launch(void* const* d_in, const int* in_sizes, int n_in,
                              void* d_out, int out_size, void* d_ws, size_t ws_size,
                              hipStream_t stream) {
    (void)in_sizes; (void)n_in; (void)out_size; (void)ws_size;
    const float* rt    = (const float*)d_in[0];
    const float* cents = (const float*)d_in[1];
    const float* attn  = (const float*)d_in[2];
    const float* sas   = (const float*)d_in[3];
    const int* num_rt  = (const int*)d_in[4];
    const int* anc     = (const int*)d_in[5];
    const int* pos     = (const int*)d_in[6];
    const int* neg     = (const int*)d_in[7];
    const float* Win   = (const float*)d_in[8];
    const float* bin   = (const float*)d_in[9];
    const float* W1    = (const float*)d_in[10];
    const float* b1    = (const float*)d_in[11];
    const float* W2    = (const float*)d_in[12];
    const float* b2    = (const float*)d_in[13];

    float* ws = (float*)d_ws;
    _Float16* feath = (_Float16*)ws;
    _Float16* featl = (_Float16*)(ws + 4194304);
    float* normF = ws + 8388608;
    float* centk = ws + 8421376;
    float* sbuf  = ws + 8552448;
    int* topidx  = (int*)(ws + 8617984);
    int* neffp   = (int*)(ws + 8650752);
    unsigned* gmask = (unsigned*)(ws + 8716352);
    _Float16* wth = (_Float16*)(ws + 8716352 + 786432);
    _Float16* wtl = (_Float16*)(ws + 8716352 + 819200);
    float* partv = (float*)(ws + 9764928);
    int*   partl = (int*)(ws + 10027072);
    float* partd = (float*)(ws + 10289216);
    float* out = (float*)d_out;

    wtrans_kernel<<<dim3(4, 4), 256, 0, stream>>>(Win, wth, wtl);
    sel_kernel<<<64, 512, 0, stream>>>(attn, cents, sas, num_rt, topidx, neffp, centk);
    feat_mfma<<<dim3(256, 2), 256, 0, stream>>>(rt, topidx, wth, wtl, bin, feath, featl);
    norm_kernel<<<8192, 256, 0, stream>>>(feath, featl, normF);
    argmin_mfma<<<dim3(4, 4, 128), 256, 0, stream>>>(feath, featl, normF, anc, pos, neg, partv, partl, partd);
    geo_kernel<<<dim3(2, 4, 128), 256, 0, stream>>>(centk, partv, partl, partd, normF, neffp, anc, pos, neg, sbuf, gmask);
    power_kernel<<<128, 1024, 0, stream>>>(gmask, sbuf, W1, b1, W2, b2, out);
}